// Round 1
// baseline (3844.295 us; speedup 1.0000x reference)
//
#include <hip/hip_runtime.h>
#include <math.h>

#define N_NODES 100000
#define N_EDGES 640000
#define IN_DIM 64
#define HID 128
#define NGRAPH 128

// ---------------------------------------------------------------------------
// fma helper: acc[i][c] += sum_kk A[i].kk * B[kk].c
// ---------------------------------------------------------------------------
__device__ __forceinline__ void fma44(const float4 A[4], const float4 B[4], float acc[4][4]) {
#pragma unroll
  for (int i2 = 0; i2 < 4; ++i2) {
    acc[i2][0] += A[i2].x*B[0].x + A[i2].y*B[1].x + A[i2].z*B[2].x + A[i2].w*B[3].x;
    acc[i2][1] += A[i2].x*B[0].y + A[i2].y*B[1].y + A[i2].z*B[2].y + A[i2].w*B[3].y;
    acc[i2][2] += A[i2].x*B[0].z + A[i2].y*B[1].z + A[i2].z*B[2].z + A[i2].w*B[3].z;
    acc[i2][3] += A[i2].x*B[0].w + A[i2].y*B[1].w + A[i2].z*B[2].w + A[i2].w*B[3].w;
  }
}

// ---------------------------------------------------------------------------
// Kernel 1: h = relu(x @ W_in.T + b_in)   x:[N,64]  W_in:[128,64]  h:[N,128]
// block: 256 threads, 32 nodes. thread (a=t/32, b=t%32): nodes 4a..4a+3, j 4b..4b+3
// ---------------------------------------------------------------------------
__global__ __launch_bounds__(256) void k_input(const float* __restrict__ x,
                                               const float* __restrict__ W,
                                               const float* __restrict__ b,
                                               float* __restrict__ h) {
  __shared__ float wS[64][132];  // wS[k][j] = W[j][k]
  __shared__ float xS[32][68];   // xS[n][k], stride 68 floats (272B, 16B aligned)
  int t = threadIdx.x;
  int nb = blockIdx.x * 32;
  // stage W: 8192 floats = 2048 float4, 8 per thread
#pragma unroll
  for (int i = 0; i < 8; ++i) {
    int idx4 = i * 256 + t;
    int j = idx4 >> 4, kq = idx4 & 15;
    float4 v = ((const float4*)W)[j * 16 + kq];
    wS[4*kq+0][j] = v.x; wS[4*kq+1][j] = v.y; wS[4*kq+2][j] = v.z; wS[4*kq+3][j] = v.w;
  }
  // stage x tile: 2048 floats = 512 float4, 2 per thread
#pragma unroll
  for (int i = 0; i < 2; ++i) {
    int idx4 = i * 256 + t;
    int n = idx4 >> 4, kq = idx4 & 15;
    float4 v = ((const float4*)x)[(nb + n) * 16 + kq];
    *((float4*)&xS[n][4*kq]) = v;
  }
  __syncthreads();
  int bq = t & 31, a = t >> 5;
  float acc[4][4] = {};
#pragma unroll
  for (int kk4 = 0; kk4 < 16; ++kk4) {
    float4 A[4], B[4];
#pragma unroll
    for (int i2 = 0; i2 < 4; ++i2) A[i2] = *((const float4*)&xS[4*a+i2][4*kk4]);
#pragma unroll
    for (int c = 0; c < 4; ++c) B[c] = *((const float4*)&wS[4*kk4+c][4*bq]);
    fma44(A, B, acc);
  }
  float4 bb = ((const float4*)b)[bq];
  float ba[4] = {bb.x, bb.y, bb.z, bb.w};
#pragma unroll
  for (int i2 = 0; i2 < 4; ++i2) {
    float4 o;
    o.x = fmaxf(acc[i2][0] + ba[0], 0.f);
    o.y = fmaxf(acc[i2][1] + ba[1], 0.f);
    o.z = fmaxf(acc[i2][2] + ba[2], 0.f);
    o.w = fmaxf(acc[i2][3] + ba[3], 0.f);
    ((float4*)h)[(nb + 4*a + i2) * 32 + bq] = o;
  }
}

// ---------------------------------------------------------------------------
// Kernel 2: m[dst] += h[src]   (atomic scatter-add), 4 edges/block, 64 lanes/edge
// ---------------------------------------------------------------------------
__global__ __launch_bounds__(256) void k_scatter(const float* __restrict__ h,
                                                 const int* __restrict__ src,
                                                 const int* __restrict__ dst,
                                                 float* __restrict__ m) {
  int t = threadIdx.x;
  int e = blockIdx.x * 4 + (t >> 6);
  int l = t & 63;
  int s = src[e], d = dst[e];
  float2 v = ((const float2*)h)[s * 64 + l];
  atomicAdd(&m[d * 128 + 2*l],     v.x);
  atomicAdd(&m[d * 128 + 2*l + 1], v.y);
}

// ---------------------------------------------------------------------------
// Kernel 3: fused MGU update (in-place on h)
//   f = sigmoid(m@Wf.T + h@Uf.T + bf); hh = tanh(m@Wh.T + (f*h)@Uh.T + bh)
//   h = (1-f)*h + f*hh
// block: 256 threads, 32 nodes; weights streamed via LDS 32-k chunks
// ---------------------------------------------------------------------------
__device__ __forceinline__ void stage_tile(const float* __restrict__ g, int nb,
                                           float S[32][132], int t) {
#pragma unroll
  for (int i = 0; i < 4; ++i) {
    int idx4 = i * 256 + t;
    int n = idx4 >> 5, kq = idx4 & 31;
    float4 v = ((const float4*)g)[(nb + n) * 32 + kq];
    *((float4*)&S[n][4*kq]) = v;
  }
}

__device__ __forceinline__ void stage_w(const float* __restrict__ W, int k0,
                                        float S[32][132], int t) {
#pragma unroll
  for (int i = 0; i < 4; ++i) {
    int idx4 = i * 256 + t;
    int j = idx4 >> 3, kq = idx4 & 7;
    float4 v = ((const float4*)W)[j * 32 + (k0 >> 2) + kq];
    S[4*kq+0][j] = v.x; S[4*kq+1][j] = v.y; S[4*kq+2][j] = v.z; S[4*kq+3][j] = v.w;
  }
}

__device__ __forceinline__ void gemm_chunk(const float S[32][132], const float W[32][132],
                                           int a, int bq, int k0, float acc[4][4]) {
#pragma unroll
  for (int kk4 = 0; kk4 < 8; ++kk4) {
    float4 A[4], B[4];
#pragma unroll
    for (int i2 = 0; i2 < 4; ++i2) A[i2] = *((const float4*)&S[4*a+i2][k0 + 4*kk4]);
#pragma unroll
    for (int c = 0; c < 4; ++c) B[c] = *((const float4*)&W[4*kk4+c][4*bq]);
    fma44(A, B, acc);
  }
}

__global__ __launch_bounds__(256) void k_mgu(float* __restrict__ h,
                                             const float* __restrict__ m,
                                             const float* __restrict__ Wf,
                                             const float* __restrict__ Uf,
                                             const float* __restrict__ bf,
                                             const float* __restrict__ Wh,
                                             const float* __restrict__ Uh,
                                             const float* __restrict__ bh) {
  __shared__ float mS[32][132];
  __shared__ float hS[32][132];
  __shared__ float gS[32][132];
  __shared__ float wS[32][132];
  int t = threadIdx.x;
  int nb = blockIdx.x * 32;
  stage_tile(m, nb, mS, t);
  stage_tile(h, nb, hS, t);
  int bq = t & 31, a = t >> 5;
  float acc[4][4] = {};
  // ---- f gate: m@Wf.T + h@Uf.T ----
  for (int kc = 0; kc < 128; kc += 32) {
    __syncthreads(); stage_w(Wf, kc, wS, t); __syncthreads();
    gemm_chunk(mS, wS, a, bq, kc, acc);
  }
  for (int kc = 0; kc < 128; kc += 32) {
    __syncthreads(); stage_w(Uf, kc, wS, t); __syncthreads();
    gemm_chunk(hS, wS, a, bq, kc, acc);
  }
  float4 bfv = ((const float4*)bf)[bq];
  float bfa[4] = {bfv.x, bfv.y, bfv.z, bfv.w};
  float f[4][4];
#pragma unroll
  for (int i2 = 0; i2 < 4; ++i2)
#pragma unroll
    for (int c = 0; c < 4; ++c) {
      f[i2][c] = 1.f / (1.f + expf(-(acc[i2][c] + bfa[c])));
      gS[4*a+i2][4*bq+c] = f[i2][c] * hS[4*a+i2][4*bq+c];
      acc[i2][c] = 0.f;
    }
  // ---- candidate: m@Wh.T + (f*h)@Uh.T ----
  for (int kc = 0; kc < 128; kc += 32) {
    __syncthreads(); stage_w(Wh, kc, wS, t); __syncthreads();
    gemm_chunk(mS, wS, a, bq, kc, acc);
  }
  for (int kc = 0; kc < 128; kc += 32) {
    __syncthreads(); stage_w(Uh, kc, wS, t); __syncthreads();
    gemm_chunk(gS, wS, a, bq, kc, acc);
  }
  float4 bhv = ((const float4*)bh)[bq];
  float bha[4] = {bhv.x, bhv.y, bhv.z, bhv.w};
#pragma unroll
  for (int i2 = 0; i2 < 4; ++i2) {
    float o[4];
#pragma unroll
    for (int c = 0; c < 4; ++c) {
      float T = tanhf(acc[i2][c] + bha[c]);
      float hv = hS[4*a+i2][4*bq+c];
      o[c] = (1.f - f[i2][c]) * hv + f[i2][c] * T;
    }
    float4 ov = {o[0], o[1], o[2], o[3]};
    ((float4*)h)[(nb + 4*a + i2) * 32 + bq] = ov;
  }
}

// ---------------------------------------------------------------------------
// Set2Set kernels
// ---------------------------------------------------------------------------
__global__ void k_bounds(const int* __restrict__ batch, int* __restrict__ startv) {
  int t = threadIdx.x;
  if (t > NGRAPH) return;
  int lo = 0, hi = N_NODES;
  while (lo < hi) { int mid = (lo + hi) >> 1; if (batch[mid] < t) lo = mid + 1; else hi = mid; }
  startv[t] = lo;
}

// LSTM cell for all graphs; one block per graph, wave-per-gate dot products
__global__ __launch_bounds__(256) void k_lstm(float* __restrict__ q_star,
                                              float* __restrict__ h_l,
                                              float* __restrict__ c_l,
                                              const float* __restrict__ w_ih,
                                              const float* __restrict__ w_hh,
                                              const float* __restrict__ b_ih,
                                              const float* __restrict__ b_hh) {
  int g = blockIdx.x, t = threadIdx.x;
  __shared__ float qsS[256];
  __shared__ float hlS[128];
  __shared__ float gateS[512];
  qsS[t] = q_star[g * 256 + t];
  if (t < 128) hlS[t] = h_l[g * 128 + t];
  __syncthreads();
  int w = t >> 6, l = t & 63;
  for (int jt = w; jt < 512; jt += 4) {
    const float* wi = w_ih + jt * 256;
    const float* wh = w_hh + jt * 128;
    float s = qsS[l] * wi[l] + qsS[l+64] * wi[l+64]
            + qsS[l+128] * wi[l+128] + qsS[l+192] * wi[l+192]
            + hlS[l] * wh[l] + hlS[l+64] * wh[l+64];
#pragma unroll
    for (int o = 32; o > 0; o >>= 1) s += __shfl_xor(s, o, 64);
    if (l == 0) gateS[jt] = s + b_ih[jt] + b_hh[jt];
  }
  __syncthreads();
  if (t < 128) {
    float gi = gateS[t], gf = gateS[128 + t], gg = gateS[256 + t], go = gateS[384 + t];
    float c = 1.f/(1.f+expf(-gf)) * c_l[g*128 + t] + 1.f/(1.f+expf(-gi)) * tanhf(gg);
    float hh = 1.f/(1.f+expf(-go)) * tanhf(c);
    c_l[g*128 + t] = c;
    h_l[g*128 + t] = hh;
    q_star[g*256 + t] = hh;  // q part of q_star
  }
}

// attention pass 1: e[n] = <h[n], q_g>, online max/sum per graph
__global__ __launch_bounds__(256) void k_attn1(const float* __restrict__ h,
                                               const float* __restrict__ q_star,
                                               const int* __restrict__ startv,
                                               float* __restrict__ e,
                                               float* __restrict__ gmax,
                                               float* __restrict__ gsum) {
  int g = blockIdx.x, t = threadIdx.x;
  __shared__ float qS[128];
  __shared__ float redM[4], redS[4];
  if (t < 128) qS[t] = q_star[g * 256 + t];
  __syncthreads();
  int s0 = startv[g], s1 = startv[g + 1];
  int w = t >> 6, l = t & 63;
  float mx = -INFINITY, sm = 0.f;
  for (int n = s0 + w; n < s1; n += 4) {
    float v = h[n*128 + l] * qS[l] + h[n*128 + 64 + l] * qS[64 + l];
#pragma unroll
    for (int o = 32; o > 0; o >>= 1) v += __shfl_xor(v, o, 64);
    if (l == 0) e[n] = v;
    float nm = fmaxf(mx, v);
    sm = sm * expf(mx - nm) + expf(v - nm);
    mx = nm;
  }
  if (l == 0) { redM[w] = mx; redS[w] = sm; }
  __syncthreads();
  if (t == 0) {
    float M = -INFINITY;
    for (int i = 0; i < 4; ++i) M = fmaxf(M, redM[i]);
    float S = 0.f;
    for (int i = 0; i < 4; ++i) if (redS[i] > 0.f) S += redS[i] * expf(redM[i] - M);
    gmax[g] = M; gsum[g] = S;
  }
}

// attention pass 2: r_g = sum_n softmax * h[n]; write into q_star[g][128:256]
__global__ __launch_bounds__(256) void k_attn2(const float* __restrict__ h,
                                               const float* __restrict__ e,
                                               const int* __restrict__ startv,
                                               const float* __restrict__ gmax,
                                               const float* __restrict__ gsum,
                                               float* __restrict__ q_star) {
  int g = blockIdx.x, t = threadIdx.x;
  int tj = t & 127, tn = t >> 7;
  int s0 = startv[g], s1 = startv[g + 1];
  float M = gmax[g];
  float sg = gsum[g];
  float inv = (sg > 0.f) ? 1.f / sg : 0.f;
  float acc = 0.f;
  for (int n = s0 + tn; n < s1; n += 2) {
    float aw = expf(e[n] - M) * inv;
    acc += aw * h[n*128 + tj];
  }
  __shared__ float red[256];
  red[t] = acc;
  __syncthreads();
  if (t < 128) q_star[g*256 + 128 + t] = red[t] + red[t + 128];
}

// prediction: out[g] = <q_star[g], W_pred> + b_pred
__global__ void k_pred(const float* __restrict__ q_star, const float* __restrict__ Wp,
                       const float* __restrict__ bp, float* __restrict__ out) {
  int g = threadIdx.x;  // 128 threads
  float s = 0.f;
  for (int k = 0; k < 256; ++k) s += q_star[g*256 + k] * Wp[k];
  out[g] = s + bp[0];
}

// ---------------------------------------------------------------------------
extern "C" void kernel_launch(void* const* d_in, const int* in_sizes, int n_in,
                              void* d_out, int out_size, void* d_ws, size_t ws_size,
                              hipStream_t stream) {
  const float* x      = (const float*)d_in[0];
  const int*   ei     = (const int*)d_in[1];
  const int*   batch  = (const int*)d_in[2];
  const float* W_in   = (const float*)d_in[3];
  const float* b_in   = (const float*)d_in[4];
  const float* W_f    = (const float*)d_in[5];
  const float* U_f    = (const float*)d_in[6];
  const float* b_f    = (const float*)d_in[7];
  const float* W_h    = (const float*)d_in[8];
  const float* U_h    = (const float*)d_in[9];
  const float* b_h    = (const float*)d_in[10];
  const float* w_ih   = (const float*)d_in[11];
  const float* w_hh   = (const float*)d_in[12];
  const float* b_ih   = (const float*)d_in[13];
  const float* b_hh   = (const float*)d_in[14];
  const float* W_pred = (const float*)d_in[15];
  const float* b_pred = (const float*)d_in[16];
  float* out = (float*)d_out;

  char* ws = (char*)d_ws;
  float* h      = (float*)(ws);                    // 51,200,000 B
  float* m      = (float*)(ws + 51200000);         // 51,200,000 B
  float* e      = (float*)(ws + 102400000);        //    400,000 B
  float* q_star = (float*)(ws + 102800000);        //    131,072 B
  float* h_l    = (float*)(ws + 102931072);        //     65,536 B
  float* c_l    = (float*)(ws + 102996608);        //     65,536 B
  float* gmax   = (float*)(ws + 103062144);        //        512 B
  float* gsum   = (float*)(ws + 103062656);        //        512 B
  int*   startv = (int*)  (ws + 103063168);        //        528 B

  k_input<<<N_NODES / 32, 256, 0, stream>>>(x, W_in, b_in, h);

  for (int step = 0; step < 3; ++step) {
    hipMemsetAsync(m, 0, (size_t)N_NODES * 128 * 4, stream);
    k_scatter<<<N_EDGES / 4, 256, 0, stream>>>(h, ei, ei + N_EDGES, m);
    k_mgu<<<N_NODES / 32, 256, 0, stream>>>(h, m, W_f, U_f, b_f, W_h, U_h, b_h);
  }

  k_bounds<<<1, 256, 0, stream>>>(batch, startv);
  hipMemsetAsync(q_star, 0, 262144, stream);  // q_star + h_l + c_l contiguous

  for (int s = 0; s < 3; ++s) {
    k_lstm<<<NGRAPH, 256, 0, stream>>>(q_star, h_l, c_l, w_ih, w_hh, b_ih, b_hh);
    k_attn1<<<NGRAPH, 256, 0, stream>>>(h, q_star, startv, e, gmax, gsum);
    k_attn2<<<NGRAPH, 256, 0, stream>>>(h, e, startv, gmax, gsum, q_star);
  }

  k_pred<<<1, 128, 0, stream>>>(q_star, W_pred, b_pred, out);
}

// Round 2
// 2485.280 us; speedup vs baseline: 1.5468x; 1.5468x over previous
//
#include <hip/hip_runtime.h>
#include <math.h>

#define N_NODES 100000
#define N_EDGES 640000
#define IN_DIM 64
#define HID 128
#define NGRAPH 128

// ---------------------------------------------------------------------------
// fma helper: acc[i][c] += sum_kk A[i].kk * B[kk].c
// ---------------------------------------------------------------------------
__device__ __forceinline__ void fma44(const float4 A[4], const float4 B[4], float acc[4][4]) {
#pragma unroll
  for (int i2 = 0; i2 < 4; ++i2) {
    acc[i2][0] += A[i2].x*B[0].x + A[i2].y*B[1].x + A[i2].z*B[2].x + A[i2].w*B[3].x;
    acc[i2][1] += A[i2].x*B[0].y + A[i2].y*B[1].y + A[i2].z*B[2].y + A[i2].w*B[3].y;
    acc[i2][2] += A[i2].x*B[0].z + A[i2].y*B[1].z + A[i2].z*B[2].z + A[i2].w*B[3].z;
    acc[i2][3] += A[i2].x*B[0].w + A[i2].y*B[1].w + A[i2].z*B[2].w + A[i2].w*B[3].w;
  }
}

// ---------------------------------------------------------------------------
// Kernel 1: h = relu(x @ W_in.T + b_in)
// ---------------------------------------------------------------------------
__global__ __launch_bounds__(256) void k_input(const float* __restrict__ x,
                                               const float* __restrict__ W,
                                               const float* __restrict__ b,
                                               float* __restrict__ h) {
  __shared__ float wS[64][132];
  __shared__ float xS[32][68];
  int t = threadIdx.x;
  int nb = blockIdx.x * 32;
#pragma unroll
  for (int i = 0; i < 8; ++i) {
    int idx4 = i * 256 + t;
    int j = idx4 >> 4, kq = idx4 & 15;
    float4 v = ((const float4*)W)[j * 16 + kq];
    wS[4*kq+0][j] = v.x; wS[4*kq+1][j] = v.y; wS[4*kq+2][j] = v.z; wS[4*kq+3][j] = v.w;
  }
#pragma unroll
  for (int i = 0; i < 2; ++i) {
    int idx4 = i * 256 + t;
    int n = idx4 >> 4, kq = idx4 & 15;
    float4 v = ((const float4*)x)[(nb + n) * 16 + kq];
    *((float4*)&xS[n][4*kq]) = v;
  }
  __syncthreads();
  int bq = t & 31, a = t >> 5;
  float acc[4][4] = {};
#pragma unroll
  for (int kk4 = 0; kk4 < 16; ++kk4) {
    float4 A[4], B[4];
#pragma unroll
    for (int i2 = 0; i2 < 4; ++i2) A[i2] = *((const float4*)&xS[4*a+i2][4*kk4]);
#pragma unroll
    for (int c = 0; c < 4; ++c) B[c] = *((const float4*)&wS[4*kk4+c][4*bq]);
    fma44(A, B, acc);
  }
  float4 bb = ((const float4*)b)[bq];
  float ba[4] = {bb.x, bb.y, bb.z, bb.w};
#pragma unroll
  for (int i2 = 0; i2 < 4; ++i2) {
    float4 o;
    o.x = fmaxf(acc[i2][0] + ba[0], 0.f);
    o.y = fmaxf(acc[i2][1] + ba[1], 0.f);
    o.z = fmaxf(acc[i2][2] + ba[2], 0.f);
    o.w = fmaxf(acc[i2][3] + ba[3], 0.f);
    ((float4*)h)[(nb + 4*a + i2) * 32 + bq] = o;
  }
}

// ---------------------------------------------------------------------------
// CSR build: histogram -> scan -> fill
// ---------------------------------------------------------------------------
__global__ __launch_bounds__(256) void k_hist(const int* __restrict__ dst,
                                              int* __restrict__ deg) {
  int e = blockIdx.x * 256 + threadIdx.x;
  if (e < N_EDGES) atomicAdd(&deg[dst[e]], 1);
}

#define SCAN_CHUNK 4096  // 256 threads x 16
#define SCAN_NB 25       // 25 * 4096 = 102400 >= 100000

__global__ __launch_bounds__(256) void k_scan_part(const int* __restrict__ deg,
                                                   int* __restrict__ bsum) {
  __shared__ int red[256];
  int t = threadIdx.x, b = blockIdx.x;
  int base = b * SCAN_CHUNK + t * 16;
  int s = 0;
#pragma unroll
  for (int i = 0; i < 16; ++i) {
    int idx = base + i;
    if (idx < N_NODES) s += deg[idx];
  }
  red[t] = s;
  __syncthreads();
  for (int off = 128; off > 0; off >>= 1) {
    if (t < off) red[t] += red[t + off];
    __syncthreads();
  }
  if (t == 0) bsum[b] = red[0];
}

__global__ void k_scan_mid(const int* __restrict__ bsum, int* __restrict__ boff,
                           int* __restrict__ rowstart) {
  if (threadIdx.x == 0) {
    int run = 0;
    for (int i = 0; i < SCAN_NB; ++i) { boff[i] = run; run += bsum[i]; }
    rowstart[N_NODES] = run;  // == N_EDGES
  }
}

__global__ __launch_bounds__(256) void k_scan_final(const int* __restrict__ deg,
                                                    const int* __restrict__ boff,
                                                    int* __restrict__ rowstart) {
  __shared__ int ts[256];
  int t = threadIdx.x, b = blockIdx.x;
  int base = b * SCAN_CHUNK + t * 16;
  int v[16];
  int s = 0;
#pragma unroll
  for (int i = 0; i < 16; ++i) {
    int idx = base + i;
    v[i] = (idx < N_NODES) ? deg[idx] : 0;
    s += v[i];
  }
  ts[t] = s;
  __syncthreads();
  // Hillis-Steele inclusive scan over 256 thread sums
  for (int off = 1; off < 256; off <<= 1) {
    int add = (t >= off) ? ts[t - off] : 0;
    __syncthreads();
    ts[t] += add;
    __syncthreads();
  }
  int run = boff[b] + ts[t] - s;  // exclusive base for this thread
#pragma unroll
  for (int i = 0; i < 16; ++i) {
    int idx = base + i;
    if (idx < N_NODES) rowstart[idx] = run;
    run += v[i];
  }
}

__global__ __launch_bounds__(256) void k_fill(const int* __restrict__ src,
                                              const int* __restrict__ dst,
                                              int* __restrict__ cursor,
                                              int* __restrict__ srcSorted) {
  int e = blockIdx.x * 256 + threadIdx.x;
  if (e >= N_EDGES) return;
  int d = dst[e];
  int p = atomicAdd(&cursor[d], 1);
  srcSorted[p] = src[e];
}

// ---------------------------------------------------------------------------
// Aggregation (gather): m[n] = sum_{j in CSR[n]} h[srcSorted[j]]
// one node per wave, lanes hold float2 (128 floats / 64 lanes)
// ---------------------------------------------------------------------------
__global__ __launch_bounds__(256) void k_gather(const float* __restrict__ h,
                                                const int* __restrict__ rowstart,
                                                const int* __restrict__ srcSorted,
                                                float* __restrict__ m) {
  int node = blockIdx.x * 4 + (threadIdx.x >> 6);
  if (node >= N_NODES) return;
  int l = threadIdx.x & 63;
  int j0 = rowstart[node], j1 = rowstart[node + 1];
  const float2* h2 = (const float2*)h;
  float2 a0 = {0.f, 0.f}, a1 = {0.f, 0.f};
  int j = j0;
  for (; j + 1 < j1; j += 2) {
    int s0 = srcSorted[j], s1 = srcSorted[j + 1];
    float2 v0 = h2[s0 * 64 + l];
    float2 v1 = h2[s1 * 64 + l];
    a0.x += v0.x; a0.y += v0.y;
    a1.x += v1.x; a1.y += v1.y;
  }
  if (j < j1) {
    int s0 = srcSorted[j];
    float2 v0 = h2[s0 * 64 + l];
    a0.x += v0.x; a0.y += v0.y;
  }
  float2 o = {a0.x + a1.x, a0.y + a1.y};
  ((float2*)m)[node * 64 + l] = o;
}

// ---------------------------------------------------------------------------
// Kernel 3: fused MGU update (in-place on h)
// ---------------------------------------------------------------------------
__device__ __forceinline__ void stage_tile(const float* __restrict__ g, int nb,
                                           float S[32][132], int t) {
#pragma unroll
  for (int i = 0; i < 4; ++i) {
    int idx4 = i * 256 + t;
    int n = idx4 >> 5, kq = idx4 & 31;
    float4 v = ((const float4*)g)[(nb + n) * 32 + kq];
    *((float4*)&S[n][4*kq]) = v;
  }
}

__device__ __forceinline__ void stage_w(const float* __restrict__ W, int k0,
                                        float S[32][132], int t) {
#pragma unroll
  for (int i = 0; i < 4; ++i) {
    int idx4 = i * 256 + t;
    int j = idx4 >> 3, kq = idx4 & 7;
    float4 v = ((const float4*)W)[j * 32 + (k0 >> 2) + kq];
    S[4*kq+0][j] = v.x; S[4*kq+1][j] = v.y; S[4*kq+2][j] = v.z; S[4*kq+3][j] = v.w;
  }
}

__device__ __forceinline__ void gemm_chunk(const float S[32][132], const float W[32][132],
                                           int a, int bq, int k0, float acc[4][4]) {
#pragma unroll
  for (int kk4 = 0; kk4 < 8; ++kk4) {
    float4 A[4], B[4];
#pragma unroll
    for (int i2 = 0; i2 < 4; ++i2) A[i2] = *((const float4*)&S[4*a+i2][k0 + 4*kk4]);
#pragma unroll
    for (int c = 0; c < 4; ++c) B[c] = *((const float4*)&W[4*kk4+c][4*bq]);
    fma44(A, B, acc);
  }
}

__global__ __launch_bounds__(256) void k_mgu(float* __restrict__ h,
                                             const float* __restrict__ m,
                                             const float* __restrict__ Wf,
                                             const float* __restrict__ Uf,
                                             const float* __restrict__ bf,
                                             const float* __restrict__ Wh,
                                             const float* __restrict__ Uh,
                                             const float* __restrict__ bh) {
  __shared__ float mS[32][132];
  __shared__ float hS[32][132];
  __shared__ float gS[32][132];
  __shared__ float wS[32][132];
  int t = threadIdx.x;
  int nb = blockIdx.x * 32;
  stage_tile(m, nb, mS, t);
  stage_tile(h, nb, hS, t);
  int bq = t & 31, a = t >> 5;
  float acc[4][4] = {};
  for (int kc = 0; kc < 128; kc += 32) {
    __syncthreads(); stage_w(Wf, kc, wS, t); __syncthreads();
    gemm_chunk(mS, wS, a, bq, kc, acc);
  }
  for (int kc = 0; kc < 128; kc += 32) {
    __syncthreads(); stage_w(Uf, kc, wS, t); __syncthreads();
    gemm_chunk(hS, wS, a, bq, kc, acc);
  }
  float4 bfv = ((const float4*)bf)[bq];
  float bfa[4] = {bfv.x, bfv.y, bfv.z, bfv.w};
  float f[4][4];
#pragma unroll
  for (int i2 = 0; i2 < 4; ++i2)
#pragma unroll
    for (int c = 0; c < 4; ++c) {
      f[i2][c] = 1.f / (1.f + expf(-(acc[i2][c] + bfa[c])));
      gS[4*a+i2][4*bq+c] = f[i2][c] * hS[4*a+i2][4*bq+c];
      acc[i2][c] = 0.f;
    }
  for (int kc = 0; kc < 128; kc += 32) {
    __syncthreads(); stage_w(Wh, kc, wS, t); __syncthreads();
    gemm_chunk(mS, wS, a, bq, kc, acc);
  }
  for (int kc = 0; kc < 128; kc += 32) {
    __syncthreads(); stage_w(Uh, kc, wS, t); __syncthreads();
    gemm_chunk(gS, wS, a, bq, kc, acc);
  }
  float4 bhv = ((const float4*)bh)[bq];
  float bha[4] = {bhv.x, bhv.y, bhv.z, bhv.w};
#pragma unroll
  for (int i2 = 0; i2 < 4; ++i2) {
    float o[4];
#pragma unroll
    for (int c = 0; c < 4; ++c) {
      float T = tanhf(acc[i2][c] + bha[c]);
      float hv = hS[4*a+i2][4*bq+c];
      o[c] = (1.f - f[i2][c]) * hv + f[i2][c] * T;
    }
    float4 ov = {o[0], o[1], o[2], o[3]};
    ((float4*)h)[(nb + 4*a + i2) * 32 + bq] = ov;
  }
}

// ---------------------------------------------------------------------------
// Set2Set kernels
// ---------------------------------------------------------------------------
__global__ void k_bounds(const int* __restrict__ batch, int* __restrict__ startv) {
  int t = threadIdx.x;
  if (t > NGRAPH) return;
  int lo = 0, hi = N_NODES;
  while (lo < hi) { int mid = (lo + hi) >> 1; if (batch[mid] < t) lo = mid + 1; else hi = mid; }
  startv[t] = lo;
}

__global__ __launch_bounds__(256) void k_lstm(float* __restrict__ q_star,
                                              float* __restrict__ h_l,
                                              float* __restrict__ c_l,
                                              const float* __restrict__ w_ih,
                                              const float* __restrict__ w_hh,
                                              const float* __restrict__ b_ih,
                                              const float* __restrict__ b_hh) {
  int g = blockIdx.x, t = threadIdx.x;
  __shared__ float qsS[256];
  __shared__ float hlS[128];
  __shared__ float gateS[512];
  qsS[t] = q_star[g * 256 + t];
  if (t < 128) hlS[t] = h_l[g * 128 + t];
  __syncthreads();
  int w = t >> 6, l = t & 63;
  for (int jt = w; jt < 512; jt += 4) {
    const float* wi = w_ih + jt * 256;
    const float* wh = w_hh + jt * 128;
    float s = qsS[l] * wi[l] + qsS[l+64] * wi[l+64]
            + qsS[l+128] * wi[l+128] + qsS[l+192] * wi[l+192]
            + hlS[l] * wh[l] + hlS[l+64] * wh[l+64];
#pragma unroll
    for (int o = 32; o > 0; o >>= 1) s += __shfl_xor(s, o, 64);
    if (l == 0) gateS[jt] = s + b_ih[jt] + b_hh[jt];
  }
  __syncthreads();
  if (t < 128) {
    float gi = gateS[t], gf = gateS[128 + t], gg = gateS[256 + t], go = gateS[384 + t];
    float c = 1.f/(1.f+expf(-gf)) * c_l[g*128 + t] + 1.f/(1.f+expf(-gi)) * tanhf(gg);
    float hh = 1.f/(1.f+expf(-go)) * tanhf(c);
    c_l[g*128 + t] = c;
    h_l[g*128 + t] = hh;
    q_star[g*256 + t] = hh;
  }
}

__global__ __launch_bounds__(256) void k_attn1(const float* __restrict__ h,
                                               const float* __restrict__ q_star,
                                               const int* __restrict__ startv,
                                               float* __restrict__ e,
                                               float* __restrict__ gmax,
                                               float* __restrict__ gsum) {
  int g = blockIdx.x, t = threadIdx.x;
  __shared__ float qS[128];
  __shared__ float redM[4], redS[4];
  if (t < 128) qS[t] = q_star[g * 256 + t];
  __syncthreads();
  int s0 = startv[g], s1 = startv[g + 1];
  int w = t >> 6, l = t & 63;
  float mx = -INFINITY, sm = 0.f;
  for (int n = s0 + w; n < s1; n += 4) {
    float v = h[n*128 + l] * qS[l] + h[n*128 + 64 + l] * qS[64 + l];
#pragma unroll
    for (int o = 32; o > 0; o >>= 1) v += __shfl_xor(v, o, 64);
    if (l == 0) e[n] = v;
    float nm = fmaxf(mx, v);
    sm = sm * expf(mx - nm) + expf(v - nm);
    mx = nm;
  }
  if (l == 0) { redM[w] = mx; redS[w] = sm; }
  __syncthreads();
  if (t == 0) {
    float M = -INFINITY;
    for (int i = 0; i < 4; ++i) M = fmaxf(M, redM[i]);
    float S = 0.f;
    for (int i = 0; i < 4; ++i) if (redS[i] > 0.f) S += redS[i] * expf(redM[i] - M);
    gmax[g] = M; gsum[g] = S;
  }
}

__global__ __launch_bounds__(256) void k_attn2(const float* __restrict__ h,
                                               const float* __restrict__ e,
                                               const int* __restrict__ startv,
                                               const float* __restrict__ gmax,
                                               const float* __restrict__ gsum,
                                               float* __restrict__ q_star) {
  int g = blockIdx.x, t = threadIdx.x;
  int tj = t & 127, tn = t >> 7;
  int s0 = startv[g], s1 = startv[g + 1];
  float M = gmax[g];
  float sg = gsum[g];
  float inv = (sg > 0.f) ? 1.f / sg : 0.f;
  float acc = 0.f;
  for (int n = s0 + tn; n < s1; n += 2) {
    float aw = expf(e[n] - M) * inv;
    acc += aw * h[n*128 + tj];
  }
  __shared__ float red[256];
  red[t] = acc;
  __syncthreads();
  if (t < 128) q_star[g*256 + 128 + t] = red[t] + red[t + 128];
}

__global__ void k_pred(const float* __restrict__ q_star, const float* __restrict__ Wp,
                       const float* __restrict__ bp, float* __restrict__ out) {
  int g = threadIdx.x;
  float s = 0.f;
  for (int k = 0; k < 256; ++k) s += q_star[g*256 + k] * Wp[k];
  out[g] = s + bp[0];
}

// ---------------------------------------------------------------------------
extern "C" void kernel_launch(void* const* d_in, const int* in_sizes, int n_in,
                              void* d_out, int out_size, void* d_ws, size_t ws_size,
                              hipStream_t stream) {
  const float* x      = (const float*)d_in[0];
  const int*   ei     = (const int*)d_in[1];
  const int*   batch  = (const int*)d_in[2];
  const float* W_in   = (const float*)d_in[3];
  const float* b_in   = (const float*)d_in[4];
  const float* W_f    = (const float*)d_in[5];
  const float* U_f    = (const float*)d_in[6];
  const float* b_f    = (const float*)d_in[7];
  const float* W_h    = (const float*)d_in[8];
  const float* U_h    = (const float*)d_in[9];
  const float* b_h    = (const float*)d_in[10];
  const float* w_ih   = (const float*)d_in[11];
  const float* w_hh   = (const float*)d_in[12];
  const float* b_ih   = (const float*)d_in[13];
  const float* b_hh   = (const float*)d_in[14];
  const float* W_pred = (const float*)d_in[15];
  const float* b_pred = (const float*)d_in[16];
  float* out = (float*)d_out;

  char* ws = (char*)d_ws;
  float* h      = (float*)(ws);                    // 51,200,000 B
  float* m      = (float*)(ws + 51200000);         // 51,200,000 B
  float* e      = (float*)(ws + 102400000);        //    400,000 B (aliased: deg, cursor)
  float* q_star = (float*)(ws + 102800000);        //    131,072 B
  float* h_l    = (float*)(ws + 102931072);        //     65,536 B
  float* c_l    = (float*)(ws + 102996608);        //     65,536 B
  float* gmax   = (float*)(ws + 103062144);        //        512 B
  float* gsum   = (float*)(ws + 103062656);        //        512 B
  int*   startv = (int*)  (ws + 103063168);        //        528 B
  int*   rowstart = (int*)(ws + 103063808);        //    400,016 B
  int*   srcSorted= (int*)(ws + 103463824);        //  2,560,000 B
  int*   bsum   = (int*)  (ws + 106023824);        //        112 B
  int*   boff   = (int*)  (ws + 106023936);        //        112 B
  // deg and cursor alias the 'e' buffer (only used before set2set)
  int* deg    = (int*)e;
  int* cursor = (int*)e;

  const int* src = ei;
  const int* dst = ei + N_EDGES;

  // ---- CSR build (once per launch; reused by all 3 MPNN steps) ----
  hipMemsetAsync(deg, 0, N_NODES * 4, stream);
  k_hist<<<(N_EDGES + 255) / 256, 256, 0, stream>>>(dst, deg);
  k_scan_part<<<SCAN_NB, 256, 0, stream>>>(deg, bsum);
  k_scan_mid<<<1, 32, 0, stream>>>(bsum, boff, rowstart);
  k_scan_final<<<SCAN_NB, 256, 0, stream>>>(deg, boff, rowstart);
  hipMemcpyAsync(cursor, rowstart, N_NODES * 4, hipMemcpyDeviceToDevice, stream);
  k_fill<<<(N_EDGES + 255) / 256, 256, 0, stream>>>(src, dst, cursor, srcSorted);

  k_input<<<N_NODES / 32, 256, 0, stream>>>(x, W_in, b_in, h);

  for (int step = 0; step < 3; ++step) {
    k_gather<<<(N_NODES + 3) / 4, 256, 0, stream>>>(h, rowstart, srcSorted, m);
    k_mgu<<<N_NODES / 32, 256, 0, stream>>>(h, m, W_f, U_f, b_f, W_h, U_h, b_h);
  }

  k_bounds<<<1, 256, 0, stream>>>(batch, startv);
  hipMemsetAsync(q_star, 0, 262144, stream);  // q_star + h_l + c_l contiguous

  for (int s = 0; s < 3; ++s) {
    k_lstm<<<NGRAPH, 256, 0, stream>>>(q_star, h_l, c_l, w_ih, w_hh, b_ih, b_hh);
    k_attn1<<<NGRAPH, 256, 0, stream>>>(h, q_star, startv, e, gmax, gsum);
    k_attn2<<<NGRAPH, 256, 0, stream>>>(h, e, startv, gmax, gsum, q_star);
  }

  k_pred<<<1, 128, 0, stream>>>(q_star, W_pred, b_pred, out);
}

// Round 3
// 2340.420 us; speedup vs baseline: 1.6426x; 1.0619x over previous
//
#include <hip/hip_runtime.h>
#include <math.h>

#define N_NODES 100000
#define N_EDGES 640000
#define IN_DIM 64
#define HID 128
#define NGRAPH 128

// ---------------------------------------------------------------------------
// fma helper: acc[i][c] += sum_kk A[i].kk * B[kk].c
// ---------------------------------------------------------------------------
__device__ __forceinline__ void fma44(const float4 A[4], const float4 B[4], float acc[4][4]) {
#pragma unroll
  for (int i2 = 0; i2 < 4; ++i2) {
    acc[i2][0] += A[i2].x*B[0].x + A[i2].y*B[1].x + A[i2].z*B[2].x + A[i2].w*B[3].x;
    acc[i2][1] += A[i2].x*B[0].y + A[i2].y*B[1].y + A[i2].z*B[2].y + A[i2].w*B[3].y;
    acc[i2][2] += A[i2].x*B[0].z + A[i2].y*B[1].z + A[i2].z*B[2].z + A[i2].w*B[3].z;
    acc[i2][3] += A[i2].x*B[0].w + A[i2].y*B[1].w + A[i2].z*B[2].w + A[i2].w*B[3].w;
  }
}

// ---------------------------------------------------------------------------
// Kernel 1: h = relu(x @ W_in.T + b_in)
// ---------------------------------------------------------------------------
__global__ __launch_bounds__(256) void k_input(const float* __restrict__ x,
                                               const float* __restrict__ W,
                                               const float* __restrict__ b,
                                               float* __restrict__ h) {
  __shared__ float wS[64][132];
  __shared__ float xS[32][68];
  int t = threadIdx.x;
  int nb = blockIdx.x * 32;
#pragma unroll
  for (int i = 0; i < 8; ++i) {
    int idx4 = i * 256 + t;
    int j = idx4 >> 4, kq = idx4 & 15;
    float4 v = ((const float4*)W)[j * 16 + kq];
    wS[4*kq+0][j] = v.x; wS[4*kq+1][j] = v.y; wS[4*kq+2][j] = v.z; wS[4*kq+3][j] = v.w;
  }
#pragma unroll
  for (int i = 0; i < 2; ++i) {
    int idx4 = i * 256 + t;
    int n = idx4 >> 4, kq = idx4 & 15;
    float4 v = ((const float4*)x)[(nb + n) * 16 + kq];
    *((float4*)&xS[n][4*kq]) = v;
  }
  __syncthreads();
  int bq = t & 31, a = t >> 5;
  float acc[4][4] = {};
#pragma unroll
  for (int kk4 = 0; kk4 < 16; ++kk4) {
    float4 A[4], B[4];
#pragma unroll
    for (int i2 = 0; i2 < 4; ++i2) A[i2] = *((const float4*)&xS[4*a+i2][4*kk4]);
#pragma unroll
    for (int c = 0; c < 4; ++c) B[c] = *((const float4*)&wS[4*kk4+c][4*bq]);
    fma44(A, B, acc);
  }
  float4 bb = ((const float4*)b)[bq];
  float ba[4] = {bb.x, bb.y, bb.z, bb.w};
#pragma unroll
  for (int i2 = 0; i2 < 4; ++i2) {
    float4 o;
    o.x = fmaxf(acc[i2][0] + ba[0], 0.f);
    o.y = fmaxf(acc[i2][1] + ba[1], 0.f);
    o.z = fmaxf(acc[i2][2] + ba[2], 0.f);
    o.w = fmaxf(acc[i2][3] + ba[3], 0.f);
    ((float4*)h)[(nb + 4*a + i2) * 32 + bq] = o;
  }
}

// ---------------------------------------------------------------------------
// CSR build: histogram -> scan -> fill
// ---------------------------------------------------------------------------
__global__ __launch_bounds__(256) void k_hist(const int* __restrict__ dst,
                                              int* __restrict__ deg) {
  int e = blockIdx.x * 256 + threadIdx.x;
  if (e < N_EDGES) atomicAdd(&deg[dst[e]], 1);
}

#define SCAN_CHUNK 4096
#define SCAN_NB 25

__global__ __launch_bounds__(256) void k_scan_part(const int* __restrict__ deg,
                                                   int* __restrict__ bsum) {
  __shared__ int red[256];
  int t = threadIdx.x, b = blockIdx.x;
  int base = b * SCAN_CHUNK + t * 16;
  int s = 0;
#pragma unroll
  for (int i = 0; i < 16; ++i) {
    int idx = base + i;
    if (idx < N_NODES) s += deg[idx];
  }
  red[t] = s;
  __syncthreads();
  for (int off = 128; off > 0; off >>= 1) {
    if (t < off) red[t] += red[t + off];
    __syncthreads();
  }
  if (t == 0) bsum[b] = red[0];
}

__global__ void k_scan_mid(const int* __restrict__ bsum, int* __restrict__ boff,
                           int* __restrict__ rowstart) {
  if (threadIdx.x == 0) {
    int run = 0;
    for (int i = 0; i < SCAN_NB; ++i) { boff[i] = run; run += bsum[i]; }
    rowstart[N_NODES] = run;
  }
}

__global__ __launch_bounds__(256) void k_scan_final(const int* __restrict__ deg,
                                                    const int* __restrict__ boff,
                                                    int* __restrict__ rowstart) {
  __shared__ int ts[256];
  int t = threadIdx.x, b = blockIdx.x;
  int base = b * SCAN_CHUNK + t * 16;
  int v[16];
  int s = 0;
#pragma unroll
  for (int i = 0; i < 16; ++i) {
    int idx = base + i;
    v[i] = (idx < N_NODES) ? deg[idx] : 0;
    s += v[i];
  }
  ts[t] = s;
  __syncthreads();
  for (int off = 1; off < 256; off <<= 1) {
    int add = (t >= off) ? ts[t - off] : 0;
    __syncthreads();
    ts[t] += add;
    __syncthreads();
  }
  int run = boff[b] + ts[t] - s;
#pragma unroll
  for (int i = 0; i < 16; ++i) {
    int idx = base + i;
    if (idx < N_NODES) rowstart[idx] = run;
    run += v[i];
  }
}

__global__ __launch_bounds__(256) void k_fill(const int* __restrict__ src,
                                              const int* __restrict__ dst,
                                              int* __restrict__ cursor,
                                              int* __restrict__ srcSorted) {
  int e = blockIdx.x * 256 + threadIdx.x;
  if (e >= N_EDGES) return;
  int d = dst[e];
  int p = atomicAdd(&cursor[d], 1);
  srcSorted[p] = src[e];
}

// ---------------------------------------------------------------------------
// One-time weight transpose: WT[k*128+j] = W[j*128+k]  (4 matrices)
// ---------------------------------------------------------------------------
__global__ __launch_bounds__(256) void k_wt(const float* __restrict__ W0,
                                            const float* __restrict__ W1,
                                            const float* __restrict__ W2,
                                            const float* __restrict__ W3,
                                            float* __restrict__ WT) {
  int id = blockIdx.x * 256 + threadIdx.x;  // grid 256 blocks -> 65536 threads
  int mat = id >> 14, rem = id & 16383;
  int j = rem >> 7, k = rem & 127;  // coalesced read along k
  const float* W = (mat == 0) ? W0 : (mat == 1) ? W1 : (mat == 2) ? W2 : W3;
  WT[mat * 16384 + k * 128 + j] = W[j * 128 + k];
}

// ---------------------------------------------------------------------------
// Aggregation (gather)
// ---------------------------------------------------------------------------
__global__ __launch_bounds__(256) void k_gather(const float* __restrict__ h,
                                                const int* __restrict__ rowstart,
                                                const int* __restrict__ srcSorted,
                                                float* __restrict__ m) {
  int node = blockIdx.x * 4 + (threadIdx.x >> 6);
  if (node >= N_NODES) return;
  int l = threadIdx.x & 63;
  int j0 = rowstart[node], j1 = rowstart[node + 1];
  const float2* h2 = (const float2*)h;
  float2 a0 = {0.f, 0.f}, a1 = {0.f, 0.f};
  int j = j0;
  for (; j + 1 < j1; j += 2) {
    int s0 = srcSorted[j], s1 = srcSorted[j + 1];
    float2 v0 = h2[s0 * 64 + l];
    float2 v1 = h2[s1 * 64 + l];
    a0.x += v0.x; a0.y += v0.y;
    a1.x += v1.x; a1.y += v1.y;
  }
  if (j < j1) {
    int s0 = srcSorted[j];
    float2 v0 = h2[s0 * 64 + l];
    a0.x += v0.x; a0.y += v0.y;
  }
  float2 o = {a0.x + a1.x, a0.y + a1.y};
  ((float2*)m)[node * 64 + l] = o;
}

// ---------------------------------------------------------------------------
// Fused MGU update (in-place on h), v2:
//   - weights pre-transposed (WT[k][j]) -> staging is coalesced float4 copy,
//     conflict-free LDS writes
//   - double-buffered weight chunks, 1 barrier per chunk
//   - hS reused for g=f*h (h saved to registers at transition)
//   LDS = mS + hS + 2x wS = 67,584 B -> 2 blocks/CU
// ---------------------------------------------------------------------------
__device__ __forceinline__ void stage_tile(const float* __restrict__ g, int nb,
                                           float S[32][132], int t) {
#pragma unroll
  for (int i = 0; i < 4; ++i) {
    int idx4 = i * 256 + t;
    int n = idx4 >> 5, kq = idx4 & 31;
    float4 v = ((const float4*)g)[(nb + n) * 32 + kq];
    *((float4*)&S[n][4*kq]) = v;
  }
}

// stage 32 rows (k0..k0+31) x 128 cols of WT into S[k][j]
__device__ __forceinline__ void stage_wt(const float* __restrict__ WT, int k0,
                                         float S[32][132], int t) {
#pragma unroll
  for (int i = 0; i < 4; ++i) {
    int idx4 = i * 256 + t;
    int k = idx4 >> 5, jq = idx4 & 31;
    float4 v = ((const float4*)WT)[(k0 + k) * 32 + jq];
    *((float4*)&S[k][4*jq]) = v;
  }
}

__device__ __forceinline__ void gemm_chunk(const float A[32][132], const float W[32][132],
                                           int a, int bq, int k0, float acc[4][4]) {
#pragma unroll
  for (int kk4 = 0; kk4 < 8; ++kk4) {
    float4 Av[4], Bv[4];
#pragma unroll
    for (int i2 = 0; i2 < 4; ++i2) Av[i2] = *((const float4*)&A[4*a+i2][k0 + 4*kk4]);
#pragma unroll
    for (int c = 0; c < 4; ++c) Bv[c] = *((const float4*)&W[4*kk4+c][4*bq]);
    fma44(Av, Bv, acc);
  }
}

__global__ __launch_bounds__(256) void k_mgu(float* __restrict__ h,
                                             const float* __restrict__ m,
                                             const float* __restrict__ WT,  // 4x [128][128] transposed
                                             const float* __restrict__ bf,
                                             const float* __restrict__ bh) {
  __shared__ float mS[32][132];
  __shared__ float hS[32][132];     // becomes gS after f-gate
  __shared__ float wS[2][32][132];
  int t = threadIdx.x;
  int nb = blockIdx.x * 32;
  stage_tile(m, nb, mS, t);
  stage_tile(h, nb, hS, t);
  stage_wt(WT, 0, wS[0], t);        // chunk 0 = Wf k0..31
  __syncthreads();

  int bq = t & 31, a = t >> 5;
  float acc[4][4] = {};
  float f[4][4], hv[4][4];

  // chunk c: phase = c>>2 (0:Wf*m, 1:Uf*h, 2:Wh*m, 3:Uh*g), k0 = (c&3)*32
  for (int c = 0; c < 16; ++c) {
    if (c + 1 < 16) {
      int cn = c + 1;
      stage_wt(WT + (cn >> 2) * 16384, (cn & 3) * 32, wS[cn & 1], t);
    }
    const float (*A)[132] = ((c >> 2) & 1) ? hS : mS;
    gemm_chunk(A, wS[c & 1], a, bq, (c & 3) * 32, acc);
    if (c == 7) {
      // f-gate done: f = sigmoid(acc + bf); save h, overwrite hS with g = f*h
      __syncthreads();  // all reads of hS (Uf phase) complete
      float4 bfv = ((const float4*)bf)[bq];
      float bfa[4] = {bfv.x, bfv.y, bfv.z, bfv.w};
#pragma unroll
      for (int i2 = 0; i2 < 4; ++i2)
#pragma unroll
        for (int c2 = 0; c2 < 4; ++c2) {
          f[i2][c2] = 1.f / (1.f + expf(-(acc[i2][c2] + bfa[c2])));
          hv[i2][c2] = hS[4*a+i2][4*bq+c2];
          hS[4*a+i2][4*bq+c2] = f[i2][c2] * hv[i2][c2];
          acc[i2][c2] = 0.f;
        }
    }
    __syncthreads();
  }

  float4 bhv = ((const float4*)bh)[bq];
  float bha[4] = {bhv.x, bhv.y, bhv.z, bhv.w};
#pragma unroll
  for (int i2 = 0; i2 < 4; ++i2) {
    float o[4];
#pragma unroll
    for (int c2 = 0; c2 < 4; ++c2) {
      float T = tanhf(acc[i2][c2] + bha[c2]);
      o[c2] = (1.f - f[i2][c2]) * hv[i2][c2] + f[i2][c2] * T;
    }
    float4 ov = {o[0], o[1], o[2], o[3]};
    ((float4*)h)[(nb + 4*a + i2) * 32 + bq] = ov;
  }
}

// ---------------------------------------------------------------------------
// Set2Set kernels
// ---------------------------------------------------------------------------
__global__ void k_bounds(const int* __restrict__ batch, int* __restrict__ startv) {
  int t = threadIdx.x;
  if (t > NGRAPH) return;
  int lo = 0, hi = N_NODES;
  while (lo < hi) { int mid = (lo + hi) >> 1; if (batch[mid] < t) lo = mid + 1; else hi = mid; }
  startv[t] = lo;
}

__global__ __launch_bounds__(256) void k_lstm(float* __restrict__ q_star,
                                              float* __restrict__ h_l,
                                              float* __restrict__ c_l,
                                              const float* __restrict__ w_ih,
                                              const float* __restrict__ w_hh,
                                              const float* __restrict__ b_ih,
                                              const float* __restrict__ b_hh) {
  int g = blockIdx.x, t = threadIdx.x;
  __shared__ float qsS[256];
  __shared__ float hlS[128];
  __shared__ float gateS[512];
  qsS[t] = q_star[g * 256 + t];
  if (t < 128) hlS[t] = h_l[g * 128 + t];
  __syncthreads();
  int w = t >> 6, l = t & 63;
  for (int jt = w; jt < 512; jt += 4) {
    const float* wi = w_ih + jt * 256;
    const float* wh = w_hh + jt * 128;
    float s = qsS[l] * wi[l] + qsS[l+64] * wi[l+64]
            + qsS[l+128] * wi[l+128] + qsS[l+192] * wi[l+192]
            + hlS[l] * wh[l] + hlS[l+64] * wh[l+64];
#pragma unroll
    for (int o = 32; o > 0; o >>= 1) s += __shfl_xor(s, o, 64);
    if (l == 0) gateS[jt] = s + b_ih[jt] + b_hh[jt];
  }
  __syncthreads();
  if (t < 128) {
    float gi = gateS[t], gf = gateS[128 + t], gg = gateS[256 + t], go = gateS[384 + t];
    float c = 1.f/(1.f+expf(-gf)) * c_l[g*128 + t] + 1.f/(1.f+expf(-gi)) * tanhf(gg);
    float hh = 1.f/(1.f+expf(-go)) * tanhf(c);
    c_l[g*128 + t] = c;
    h_l[g*128 + t] = hh;
    q_star[g*256 + t] = hh;
  }
}

__global__ __launch_bounds__(256) void k_attn1(const float* __restrict__ h,
                                               const float* __restrict__ q_star,
                                               const int* __restrict__ startv,
                                               float* __restrict__ e,
                                               float* __restrict__ gmax,
                                               float* __restrict__ gsum) {
  int g = blockIdx.x, t = threadIdx.x;
  __shared__ float qS[128];
  __shared__ float redM[4], redS[4];
  if (t < 128) qS[t] = q_star[g * 256 + t];
  __syncthreads();
  int s0 = startv[g], s1 = startv[g + 1];
  int w = t >> 6, l = t & 63;
  float mx = -INFINITY, sm = 0.f;
  for (int n = s0 + w; n < s1; n += 4) {
    float v = h[n*128 + l] * qS[l] + h[n*128 + 64 + l] * qS[64 + l];
#pragma unroll
    for (int o = 32; o > 0; o >>= 1) v += __shfl_xor(v, o, 64);
    if (l == 0) e[n] = v;
    float nm = fmaxf(mx, v);
    sm = sm * expf(mx - nm) + expf(v - nm);
    mx = nm;
  }
  if (l == 0) { redM[w] = mx; redS[w] = sm; }
  __syncthreads();
  if (t == 0) {
    float M = -INFINITY;
    for (int i = 0; i < 4; ++i) M = fmaxf(M, redM[i]);
    float S = 0.f;
    for (int i = 0; i < 4; ++i) if (redS[i] > 0.f) S += redS[i] * expf(redM[i] - M);
    gmax[g] = M; gsum[g] = S;
  }
}

__global__ __launch_bounds__(256) void k_attn2(const float* __restrict__ h,
                                               const float* __restrict__ e,
                                               const int* __restrict__ startv,
                                               const float* __restrict__ gmax,
                                               const float* __restrict__ gsum,
                                               float* __restrict__ q_star) {
  int g = blockIdx.x, t = threadIdx.x;
  int tj = t & 127, tn = t >> 7;
  int s0 = startv[g], s1 = startv[g + 1];
  float M = gmax[g];
  float sg = gsum[g];
  float inv = (sg > 0.f) ? 1.f / sg : 0.f;
  float acc = 0.f;
  for (int n = s0 + tn; n < s1; n += 2) {
    float aw = expf(e[n] - M) * inv;
    acc += aw * h[n*128 + tj];
  }
  __shared__ float red[256];
  red[t] = acc;
  __syncthreads();
  if (t < 128) q_star[g*256 + 128 + t] = red[t] + red[t + 128];
}

__global__ void k_pred(const float* __restrict__ q_star, const float* __restrict__ Wp,
                       const float* __restrict__ bp, float* __restrict__ out) {
  int g = threadIdx.x;
  float s = 0.f;
  for (int k = 0; k < 256; ++k) s += q_star[g*256 + k] * Wp[k];
  out[g] = s + bp[0];
}

// ---------------------------------------------------------------------------
extern "C" void kernel_launch(void* const* d_in, const int* in_sizes, int n_in,
                              void* d_out, int out_size, void* d_ws, size_t ws_size,
                              hipStream_t stream) {
  const float* x      = (const float*)d_in[0];
  const int*   ei     = (const int*)d_in[1];
  const int*   batch  = (const int*)d_in[2];
  const float* W_in   = (const float*)d_in[3];
  const float* b_in   = (const float*)d_in[4];
  const float* W_f    = (const float*)d_in[5];
  const float* U_f    = (const float*)d_in[6];
  const float* b_f    = (const float*)d_in[7];
  const float* W_h    = (const float*)d_in[8];
  const float* U_h    = (const float*)d_in[9];
  const float* b_h    = (const float*)d_in[10];
  const float* w_ih   = (const float*)d_in[11];
  const float* w_hh   = (const float*)d_in[12];
  const float* b_ih   = (const float*)d_in[13];
  const float* b_hh   = (const float*)d_in[14];
  const float* W_pred = (const float*)d_in[15];
  const float* b_pred = (const float*)d_in[16];
  float* out = (float*)d_out;

  char* ws = (char*)d_ws;
  float* h      = (float*)(ws);                    // 51,200,000 B
  float* m      = (float*)(ws + 51200000);         // 51,200,000 B
  float* e      = (float*)(ws + 102400000);        //    400,000 B (aliased: deg, cursor, WT)
  float* q_star = (float*)(ws + 102800000);        //    131,072 B
  float* h_l    = (float*)(ws + 102931072);        //     65,536 B
  float* c_l    = (float*)(ws + 102996608);        //     65,536 B
  float* gmax   = (float*)(ws + 103062144);        //        512 B
  float* gsum   = (float*)(ws + 103062656);        //        512 B
  int*   startv = (int*)  (ws + 103063168);        //        528 B
  int*   rowstart = (int*)(ws + 103063808);        //    400,016 B
  int*   srcSorted= (int*)(ws + 103463824);        //  2,560,000 B
  int*   bsum   = (int*)  (ws + 106023824);        //        112 B
  int*   boff   = (int*)  (ws + 106023936);        //        112 B
  // Lifetimes in the 'e' buffer (400,000 B):
  //   deg/cursor: CSR build only (before k_wt)
  //   WT (262,144 B): MPNN loop only (before attn)
  //   e scores: set2set only
  int* deg    = (int*)e;
  int* cursor = (int*)e;
  float* WT   = (float*)e;

  const int* src = ei;
  const int* dst = ei + N_EDGES;

  // ---- CSR build (once; reused by all 3 MPNN steps) ----
  hipMemsetAsync(deg, 0, N_NODES * 4, stream);
  k_hist<<<(N_EDGES + 255) / 256, 256, 0, stream>>>(dst, deg);
  k_scan_part<<<SCAN_NB, 256, 0, stream>>>(deg, bsum);
  k_scan_mid<<<1, 32, 0, stream>>>(bsum, boff, rowstart);
  k_scan_final<<<SCAN_NB, 256, 0, stream>>>(deg, boff, rowstart);
  hipMemcpyAsync(cursor, rowstart, N_NODES * 4, hipMemcpyDeviceToDevice, stream);
  k_fill<<<(N_EDGES + 255) / 256, 256, 0, stream>>>(src, dst, cursor, srcSorted);

  // ---- one-time weight transpose (WT overwrites deg/cursor region) ----
  k_wt<<<256, 256, 0, stream>>>(W_f, U_f, W_h, U_h, WT);

  k_input<<<N_NODES / 32, 256, 0, stream>>>(x, W_in, b_in, h);

  for (int step = 0; step < 3; ++step) {
    k_gather<<<(N_NODES + 3) / 4, 256, 0, stream>>>(h, rowstart, srcSorted, m);
    k_mgu<<<N_NODES / 32, 256, 0, stream>>>(h, m, WT, b_f, b_h);
  }

  k_bounds<<<1, 256, 0, stream>>>(batch, startv);
  hipMemsetAsync(q_star, 0, 262144, stream);

  for (int s = 0; s < 3; ++s) {
    k_lstm<<<NGRAPH, 256, 0, stream>>>(q_star, h_l, c_l, w_ih, w_hh, b_ih, b_hh);
    k_attn1<<<NGRAPH, 256, 0, stream>>>(h, q_star, startv, e, gmax, gsum);
    k_attn2<<<NGRAPH, 256, 0, stream>>>(h, e, startv, gmax, gsum, q_star);
  }

  k_pred<<<1, 128, 0, stream>>>(q_star, W_pred, b_pred, out);
}

// Round 4
// 1706.103 us; speedup vs baseline: 2.2533x; 1.3718x over previous
//
#include <hip/hip_runtime.h>
#include <math.h>

#define N_NODES 100000
#define N_EDGES 640000
#define IN_DIM 64
#define HID 128
#define NGRAPH 128

typedef __bf16 bf16x4 __attribute__((ext_vector_type(4)));
typedef __bf16 bf16x8 __attribute__((ext_vector_type(8)));
typedef float f32x4 __attribute__((ext_vector_type(4)));

#define LDST 136  // bf16 elements per LDS row: 272 B, 16B-aligned, breaks pow2 stride

// ---------------------------------------------------------------------------
// fma helper (used by k_input only)
// ---------------------------------------------------------------------------
__device__ __forceinline__ void fma44(const float4 A[4], const float4 B[4], float acc[4][4]) {
#pragma unroll
  for (int i2 = 0; i2 < 4; ++i2) {
    acc[i2][0] += A[i2].x*B[0].x + A[i2].y*B[1].x + A[i2].z*B[2].x + A[i2].w*B[3].x;
    acc[i2][1] += A[i2].x*B[0].y + A[i2].y*B[1].y + A[i2].z*B[2].y + A[i2].w*B[3].y;
    acc[i2][2] += A[i2].x*B[0].z + A[i2].y*B[1].z + A[i2].z*B[2].z + A[i2].w*B[3].z;
    acc[i2][3] += A[i2].x*B[0].w + A[i2].y*B[1].w + A[i2].z*B[2].w + A[i2].w*B[3].w;
  }
}

// ---------------------------------------------------------------------------
// Kernel 1: h = relu(x @ W_in.T + b_in)
// ---------------------------------------------------------------------------
__global__ __launch_bounds__(256) void k_input(const float* __restrict__ x,
                                               const float* __restrict__ W,
                                               const float* __restrict__ b,
                                               float* __restrict__ h) {
  __shared__ float wS[64][132];
  __shared__ float xS[32][68];
  int t = threadIdx.x;
  int nb = blockIdx.x * 32;
#pragma unroll
  for (int i = 0; i < 8; ++i) {
    int idx4 = i * 256 + t;
    int j = idx4 >> 4, kq = idx4 & 15;
    float4 v = ((const float4*)W)[j * 16 + kq];
    wS[4*kq+0][j] = v.x; wS[4*kq+1][j] = v.y; wS[4*kq+2][j] = v.z; wS[4*kq+3][j] = v.w;
  }
#pragma unroll
  for (int i = 0; i < 2; ++i) {
    int idx4 = i * 256 + t;
    int n = idx4 >> 4, kq = idx4 & 15;
    float4 v = ((const float4*)x)[(nb + n) * 16 + kq];
    *((float4*)&xS[n][4*kq]) = v;
  }
  __syncthreads();
  int bq = t & 31, a = t >> 5;
  float acc[4][4] = {};
#pragma unroll
  for (int kk4 = 0; kk4 < 16; ++kk4) {
    float4 A[4], B[4];
#pragma unroll
    for (int i2 = 0; i2 < 4; ++i2) A[i2] = *((const float4*)&xS[4*a+i2][4*kk4]);
#pragma unroll
    for (int c = 0; c < 4; ++c) B[c] = *((const float4*)&wS[4*kk4+c][4*bq]);
    fma44(A, B, acc);
  }
  float4 bb = ((const float4*)b)[bq];
  float ba[4] = {bb.x, bb.y, bb.z, bb.w};
#pragma unroll
  for (int i2 = 0; i2 < 4; ++i2) {
    float4 o;
    o.x = fmaxf(acc[i2][0] + ba[0], 0.f);
    o.y = fmaxf(acc[i2][1] + ba[1], 0.f);
    o.z = fmaxf(acc[i2][2] + ba[2], 0.f);
    o.w = fmaxf(acc[i2][3] + ba[3], 0.f);
    ((float4*)h)[(nb + 4*a + i2) * 32 + bq] = o;
  }
}

// ---------------------------------------------------------------------------
// CSR build: histogram -> scan -> fill
// ---------------------------------------------------------------------------
__global__ __launch_bounds__(256) void k_hist(const int* __restrict__ dst,
                                              int* __restrict__ deg) {
  int e = blockIdx.x * 256 + threadIdx.x;
  if (e < N_EDGES) atomicAdd(&deg[dst[e]], 1);
}

#define SCAN_CHUNK 4096
#define SCAN_NB 25

__global__ __launch_bounds__(256) void k_scan_part(const int* __restrict__ deg,
                                                   int* __restrict__ bsum) {
  __shared__ int red[256];
  int t = threadIdx.x, b = blockIdx.x;
  int base = b * SCAN_CHUNK + t * 16;
  int s = 0;
#pragma unroll
  for (int i = 0; i < 16; ++i) {
    int idx = base + i;
    if (idx < N_NODES) s += deg[idx];
  }
  red[t] = s;
  __syncthreads();
  for (int off = 128; off > 0; off >>= 1) {
    if (t < off) red[t] += red[t + off];
    __syncthreads();
  }
  if (t == 0) bsum[b] = red[0];
}

__global__ void k_scan_mid(const int* __restrict__ bsum, int* __restrict__ boff,
                           int* __restrict__ rowstart) {
  if (threadIdx.x == 0) {
    int run = 0;
    for (int i = 0; i < SCAN_NB; ++i) { boff[i] = run; run += bsum[i]; }
    rowstart[N_NODES] = run;
  }
}

__global__ __launch_bounds__(256) void k_scan_final(const int* __restrict__ deg,
                                                    const int* __restrict__ boff,
                                                    int* __restrict__ rowstart) {
  __shared__ int ts[256];
  int t = threadIdx.x, b = blockIdx.x;
  int base = b * SCAN_CHUNK + t * 16;
  int v[16];
  int s = 0;
#pragma unroll
  for (int i = 0; i < 16; ++i) {
    int idx = base + i;
    v[i] = (idx < N_NODES) ? deg[idx] : 0;
    s += v[i];
  }
  ts[t] = s;
  __syncthreads();
  for (int off = 1; off < 256; off <<= 1) {
    int add = (t >= off) ? ts[t - off] : 0;
    __syncthreads();
    ts[t] += add;
    __syncthreads();
  }
  int run = boff[b] + ts[t] - s;
#pragma unroll
  for (int i = 0; i < 16; ++i) {
    int idx = base + i;
    if (idx < N_NODES) rowstart[idx] = run;
    run += v[i];
  }
}

__global__ __launch_bounds__(256) void k_fill(const int* __restrict__ src,
                                              const int* __restrict__ dst,
                                              int* __restrict__ cursor,
                                              int* __restrict__ srcSorted) {
  int e = blockIdx.x * 256 + threadIdx.x;
  if (e >= N_EDGES) return;
  int d = dst[e];
  int p = atomicAdd(&cursor[d], 1);
  srcSorted[p] = src[e];
}

// ---------------------------------------------------------------------------
// One-time weight split fp32 -> bf16 (hi, lo). Layout preserved: [mat][j][k]
// mats: 0=W_f, 1=U_f, 2=W_h, 3=U_h
// ---------------------------------------------------------------------------
__global__ __launch_bounds__(256) void k_wsplit(const float* __restrict__ W0,
                                                const float* __restrict__ W1,
                                                const float* __restrict__ W2,
                                                const float* __restrict__ W3,
                                                __bf16* __restrict__ Whi,
                                                __bf16* __restrict__ Wlo) {
  int id = blockIdx.x * 256 + threadIdx.x;  // 65536 total
  int mat = id >> 14, idx = id & 16383;
  const float* W = (mat == 0) ? W0 : (mat == 1) ? W1 : (mat == 2) ? W2 : W3;
  float v = W[idx];
  __bf16 hi = (__bf16)v;
  Whi[id] = hi;
  Wlo[id] = (__bf16)(v - (float)hi);
}

// ---------------------------------------------------------------------------
// Aggregation (gather)
// ---------------------------------------------------------------------------
__global__ __launch_bounds__(256) void k_gather(const float* __restrict__ h,
                                                const int* __restrict__ rowstart,
                                                const int* __restrict__ srcSorted,
                                                float* __restrict__ m) {
  int node = blockIdx.x * 4 + (threadIdx.x >> 6);
  if (node >= N_NODES) return;
  int l = threadIdx.x & 63;
  int j0 = rowstart[node], j1 = rowstart[node + 1];
  const float2* h2 = (const float2*)h;
  float2 a0 = {0.f, 0.f}, a1 = {0.f, 0.f};
  int j = j0;
  for (; j + 1 < j1; j += 2) {
    int s0 = srcSorted[j], s1 = srcSorted[j + 1];
    float2 v0 = h2[s0 * 64 + l];
    float2 v1 = h2[s1 * 64 + l];
    a0.x += v0.x; a0.y += v0.y;
    a1.x += v1.x; a1.y += v1.y;
  }
  if (j < j1) {
    int s0 = srcSorted[j];
    float2 v0 = h2[s0 * 64 + l];
    a0.x += v0.x; a0.y += v0.y;
  }
  float2 o = {a0.x + a1.x, a0.y + a1.y};
  ((float2*)m)[node * 64 + l] = o;
}

// ---------------------------------------------------------------------------
// Fused MGU update, MFMA split-bf16 version.
// 32 nodes/block, 4 waves. Wave w owns col-tiles {2w, 2w+1} x row-tiles {0,1}
// (16x16 output tiles). fp32 operands split to bf16 hi/lo; each product is
// 3 MFMAs (hi*hi + hi*lo + lo*hi), fp32 accumulate.
// Verified layouts (cdna_hip_programming.md s3/s5):
//   A-frag: A[m=lane&15][k=(lane>>4)*8 + j]   (8 consecutive bf16 -> b128)
//   B-frag: B[k=(lane>>4)*8 + j][n=lane&15]  == W[j=lane&15][k consecutive]
//           -> original row-major W, no transpose
//   C/D:    col = lane&15, row = (lane>>4)*4 + reg
// ---------------------------------------------------------------------------
__global__ __launch_bounds__(256) void k_mgu(float* __restrict__ h,
                                             const float* __restrict__ m,
                                             const __bf16* __restrict__ Whi,
                                             const __bf16* __restrict__ Wlo,
                                             const float* __restrict__ bfp,
                                             const float* __restrict__ bhp) {
  __shared__ __bf16 mHi[32 * LDST], mLo[32 * LDST];
  __shared__ __bf16 hHi[32 * LDST], hLo[32 * LDST];
  __shared__ __bf16 gHi[32 * LDST], gLo[32 * LDST];
  const int t = threadIdx.x;
  const int nb = blockIdx.x * 32;

  // ---- stage m,h tiles; split to bf16 hi/lo in LDS ----
#pragma unroll
  for (int i = 0; i < 4; ++i) {
    int idx4 = i * 256 + t;
    int n = idx4 >> 5, kq = idx4 & 31;
    float4 vm = ((const float4*)m)[(nb + n) * 32 + kq];
    float4 vh = ((const float4*)h)[(nb + n) * 32 + kq];
    bf16x4 mh, ml, hh, hl;
    mh[0] = (__bf16)vm.x; ml[0] = (__bf16)(vm.x - (float)mh[0]);
    mh[1] = (__bf16)vm.y; ml[1] = (__bf16)(vm.y - (float)mh[1]);
    mh[2] = (__bf16)vm.z; ml[2] = (__bf16)(vm.z - (float)mh[2]);
    mh[3] = (__bf16)vm.w; ml[3] = (__bf16)(vm.w - (float)mh[3]);
    hh[0] = (__bf16)vh.x; hl[0] = (__bf16)(vh.x - (float)hh[0]);
    hh[1] = (__bf16)vh.y; hl[1] = (__bf16)(vh.y - (float)hh[1]);
    hh[2] = (__bf16)vh.z; hl[2] = (__bf16)(vh.z - (float)hh[2]);
    hh[3] = (__bf16)vh.w; hl[3] = (__bf16)(vh.w - (float)hh[3]);
    int e0 = n * LDST + 4 * kq;
    *(bf16x4*)&mHi[e0] = mh; *(bf16x4*)&mLo[e0] = ml;
    *(bf16x4*)&hHi[e0] = hh; *(bf16x4*)&hLo[e0] = hl;
  }
  __syncthreads();

  const int w = t >> 6, l = t & 63;
  const int lj = l & 15, q = l >> 4;

  float bfj[2], bhj[2];
#pragma unroll
  for (int ct = 0; ct < 2; ++ct) {
    int j = (2 * w + ct) * 16 + lj;
    bfj[ct] = bfp[j];
    bhj[ct] = bhp[j];
  }

  f32x4 acc[2][2] = {};

  // ---- phase A: z_f = m@Wf.T + h@Uf.T ----
#pragma unroll
  for (int kc = 0; kc < 128; kc += 32) {
    bf16x8 amh[2], aml[2], ahh[2], ahl[2];
#pragma unroll
    for (int rt = 0; rt < 2; ++rt) {
      int e0 = (rt * 16 + lj) * LDST + kc + q * 8;
      amh[rt] = *(const bf16x8*)&mHi[e0];
      aml[rt] = *(const bf16x8*)&mLo[e0];
      ahh[rt] = *(const bf16x8*)&hHi[e0];
      ahl[rt] = *(const bf16x8*)&hLo[e0];
    }
    bf16x8 bwh[2], bwl[2], buh[2], bul[2];
#pragma unroll
    for (int ct = 0; ct < 2; ++ct) {
      int off = ((2 * w + ct) * 16 + lj) * 128 + kc + q * 8;
      bwh[ct] = *(const bf16x8*)&Whi[off];            // W_f hi
      bwl[ct] = *(const bf16x8*)&Wlo[off];
      buh[ct] = *(const bf16x8*)&Whi[16384 + off];    // U_f hi
      bul[ct] = *(const bf16x8*)&Wlo[16384 + off];
    }
#pragma unroll
    for (int rt = 0; rt < 2; ++rt)
#pragma unroll
      for (int ct = 0; ct < 2; ++ct) {
        f32x4 a = acc[rt][ct];
        a = __builtin_amdgcn_mfma_f32_16x16x32_bf16(amh[rt], bwh[ct], a, 0, 0, 0);
        a = __builtin_amdgcn_mfma_f32_16x16x32_bf16(amh[rt], bwl[ct], a, 0, 0, 0);
        a = __builtin_amdgcn_mfma_f32_16x16x32_bf16(aml[rt], bwh[ct], a, 0, 0, 0);
        a = __builtin_amdgcn_mfma_f32_16x16x32_bf16(ahh[rt], buh[ct], a, 0, 0, 0);
        a = __builtin_amdgcn_mfma_f32_16x16x32_bf16(ahh[rt], bul[ct], a, 0, 0, 0);
        a = __builtin_amdgcn_mfma_f32_16x16x32_bf16(ahl[rt], buh[ct], a, 0, 0, 0);
        acc[rt][ct] = a;
      }
  }

  // ---- transition: f = sigmoid(z_f + bf); g = f*h into LDS (bf16 split) ----
  float fv[2][2][4], hvv[2][2][4];
#pragma unroll
  for (int rt = 0; rt < 2; ++rt)
#pragma unroll
    for (int ct = 0; ct < 2; ++ct) {
      int j = (2 * w + ct) * 16 + lj;
#pragma unroll
      for (int r = 0; r < 4; ++r) {
        int nl = rt * 16 + q * 4 + r;
        float z = acc[rt][ct][r] + bfj[ct];
        float f = 1.f / (1.f + expf(-z));
        int he = nl * LDST + j;
        float hval = (float)hHi[he] + (float)hLo[he];
        float g = f * hval;
        __bf16 ghi = (__bf16)g;
        gHi[he] = ghi;
        gLo[he] = (__bf16)(g - (float)ghi);
        fv[rt][ct][r] = f;
        hvv[rt][ct][r] = hval;
        acc[rt][ct][r] = 0.f;
      }
    }
  __syncthreads();

  // ---- phase B: z_h = m@Wh.T + g@Uh.T ----
#pragma unroll
  for (int kc = 0; kc < 128; kc += 32) {
    bf16x8 amh[2], aml[2], agh[2], agl[2];
#pragma unroll
    for (int rt = 0; rt < 2; ++rt) {
      int e0 = (rt * 16 + lj) * LDST + kc + q * 8;
      amh[rt] = *(const bf16x8*)&mHi[e0];
      aml[rt] = *(const bf16x8*)&mLo[e0];
      agh[rt] = *(const bf16x8*)&gHi[e0];
      agl[rt] = *(const bf16x8*)&gLo[e0];
    }
    bf16x8 bwh[2], bwl[2], buh[2], bul[2];
#pragma unroll
    for (int ct = 0; ct < 2; ++ct) {
      int off = ((2 * w + ct) * 16 + lj) * 128 + kc + q * 8;
      bwh[ct] = *(const bf16x8*)&Whi[2 * 16384 + off];  // W_h hi
      bwl[ct] = *(const bf16x8*)&Wlo[2 * 16384 + off];
      buh[ct] = *(const bf16x8*)&Whi[3 * 16384 + off];  // U_h hi
      bul[ct] = *(const bf16x8*)&Wlo[3 * 16384 + off];
    }
#pragma unroll
    for (int rt = 0; rt < 2; ++rt)
#pragma unroll
      for (int ct = 0; ct < 2; ++ct) {
        f32x4 a = acc[rt][ct];
        a = __builtin_amdgcn_mfma_f32_16x16x32_bf16(amh[rt], bwh[ct], a, 0, 0, 0);
        a = __builtin_amdgcn_mfma_f32_16x16x32_bf16(amh[rt], bwl[ct], a, 0, 0, 0);
        a = __builtin_amdgcn_mfma_f32_16x16x32_bf16(aml[rt], bwh[ct], a, 0, 0, 0);
        a = __builtin_amdgcn_mfma_f32_16x16x32_bf16(agh[rt], buh[ct], a, 0, 0, 0);
        a = __builtin_amdgcn_mfma_f32_16x16x32_bf16(agh[rt], bul[ct], a, 0, 0, 0);
        a = __builtin_amdgcn_mfma_f32_16x16x32_bf16(agl[rt], buh[ct], a, 0, 0, 0);
        acc[rt][ct] = a;
      }
  }

  // ---- epilogue: h = (1-f)*h + f*tanh(z_h + bh) ----
#pragma unroll
  for (int rt = 0; rt < 2; ++rt)
#pragma unroll
    for (int ct = 0; ct < 2; ++ct) {
      int j = (2 * w + ct) * 16 + lj;
#pragma unroll
      for (int r = 0; r < 4; ++r) {
        float T = tanhf(acc[rt][ct][r] + bhj[ct]);
        float f = fv[rt][ct][r];
        float hn = (1.f - f) * hvv[rt][ct][r] + f * T;
        h[(nb + rt * 16 + q * 4 + r) * 128 + j] = hn;
      }
    }
}

// ---------------------------------------------------------------------------
// Set2Set kernels
// ---------------------------------------------------------------------------
__global__ void k_bounds(const int* __restrict__ batch, int* __restrict__ startv) {
  int t = threadIdx.x;
  if (t > NGRAPH) return;
  int lo = 0, hi = N_NODES;
  while (lo < hi) { int mid = (lo + hi) >> 1; if (batch[mid] < t) lo = mid + 1; else hi = mid; }
  startv[t] = lo;
}

__global__ __launch_bounds__(256) void k_lstm(float* __restrict__ q_star,
                                              float* __restrict__ h_l,
                                              float* __restrict__ c_l,
                                              const float* __restrict__ w_ih,
                                              const float* __restrict__ w_hh,
                                              const float* __restrict__ b_ih,
                                              const float* __restrict__ b_hh) {
  int g = blockIdx.x, t = threadIdx.x;
  __shared__ float qsS[256];
  __shared__ float hlS[128];
  __shared__ float gateS[512];
  qsS[t] = q_star[g * 256 + t];
  if (t < 128) hlS[t] = h_l[g * 128 + t];
  __syncthreads();
  int w = t >> 6, l = t & 63;
  for (int jt = w; jt < 512; jt += 4) {
    const float* wi = w_ih + jt * 256;
    const float* wh = w_hh + jt * 128;
    float s = qsS[l] * wi[l] + qsS[l+64] * wi[l+64]
            + qsS[l+128] * wi[l+128] + qsS[l+192] * wi[l+192]
            + hlS[l] * wh[l] + hlS[l+64] * wh[l+64];
#pragma unroll
    for (int o = 32; o > 0; o >>= 1) s += __shfl_xor(s, o, 64);
    if (l == 0) gateS[jt] = s + b_ih[jt] + b_hh[jt];
  }
  __syncthreads();
  if (t < 128) {
    float gi = gateS[t], gf = gateS[128 + t], gg = gateS[256 + t], go = gateS[384 + t];
    float c = 1.f/(1.f+expf(-gf)) * c_l[g*128 + t] + 1.f/(1.f+expf(-gi)) * tanhf(gg);
    float hh = 1.f/(1.f+expf(-go)) * tanhf(c);
    c_l[g*128 + t] = c;
    h_l[g*128 + t] = hh;
    q_star[g*256 + t] = hh;
  }
}

__global__ __launch_bounds__(256) void k_attn1(const float* __restrict__ h,
                                               const float* __restrict__ q_star,
                                               const int* __restrict__ startv,
                                               float* __restrict__ e,
                                               float* __restrict__ gmax,
                                               float* __restrict__ gsum) {
  int g = blockIdx.x, t = threadIdx.x;
  __shared__ float qS[128];
  __shared__ float redM[4], redS[4];
  if (t < 128) qS[t] = q_star[g * 256 + t];
  __syncthreads();
  int s0 = startv[g], s1 = startv[g + 1];
  int w = t >> 6, l = t & 63;
  float mx = -INFINITY, sm = 0.f;
  for (int n = s0 + w; n < s1; n += 4) {
    float v = h[n*128 + l] * qS[l] + h[n*128 + 64 + l] * qS[64 + l];
#pragma unroll
    for (int o = 32; o > 0; o >>= 1) v += __shfl_xor(v, o, 64);
    if (l == 0) e[n] = v;
    float nm = fmaxf(mx, v);
    sm = sm * expf(mx - nm) + expf(v - nm);
    mx = nm;
  }
  if (l == 0) { redM[w] = mx; redS[w] = sm; }
  __syncthreads();
  if (t == 0) {
    float M = -INFINITY;
    for (int i = 0; i < 4; ++i) M = fmaxf(M, redM[i]);
    float S = 0.f;
    for (int i = 0; i < 4; ++i) if (redS[i] > 0.f) S += redS[i] * expf(redM[i] - M);
    gmax[g] = M; gsum[g] = S;
  }
}

__global__ __launch_bounds__(256) void k_attn2(const float* __restrict__ h,
                                               const float* __restrict__ e,
                                               const int* __restrict__ startv,
                                               const float* __restrict__ gmax,
                                               const float* __restrict__ gsum,
                                               float* __restrict__ q_star) {
  int g = blockIdx.x, t = threadIdx.x;
  int tj = t & 127, tn = t >> 7;
  int s0 = startv[g], s1 = startv[g + 1];
  float M = gmax[g];
  float sg = gsum[g];
  float inv = (sg > 0.f) ? 1.f / sg : 0.f;
  float acc = 0.f;
  for (int n = s0 + tn; n < s1; n += 2) {
    float aw = expf(e[n] - M) * inv;
    acc += aw * h[n*128 + tj];
  }
  __shared__ float red[256];
  red[t] = acc;
  __syncthreads();
  if (t < 128) q_star[g*256 + 128 + t] = red[t] + red[t + 128];
}

__global__ void k_pred(const float* __restrict__ q_star, const float* __restrict__ Wp,
                       const float* __restrict__ bp, float* __restrict__ out) {
  int g = threadIdx.x;
  float s = 0.f;
  for (int k = 0; k < 256; ++k) s += q_star[g*256 + k] * Wp[k];
  out[g] = s + bp[0];
}

// ---------------------------------------------------------------------------
extern "C" void kernel_launch(void* const* d_in, const int* in_sizes, int n_in,
                              void* d_out, int out_size, void* d_ws, size_t ws_size,
                              hipStream_t stream) {
  const float* x      = (const float*)d_in[0];
  const int*   ei     = (const int*)d_in[1];
  const int*   batch  = (const int*)d_in[2];
  const float* W_in   = (const float*)d_in[3];
  const float* b_in   = (const float*)d_in[4];
  const float* W_f    = (const float*)d_in[5];
  const float* U_f    = (const float*)d_in[6];
  const float* b_f    = (const float*)d_in[7];
  const float* W_h    = (const float*)d_in[8];
  const float* U_h    = (const float*)d_in[9];
  const float* b_h    = (const float*)d_in[10];
  const float* w_ih   = (const float*)d_in[11];
  const float* w_hh   = (const float*)d_in[12];
  const float* b_ih   = (const float*)d_in[13];
  const float* b_hh   = (const float*)d_in[14];
  const float* W_pred = (const float*)d_in[15];
  const float* b_pred = (const float*)d_in[16];
  float* out = (float*)d_out;

  char* ws = (char*)d_ws;
  float* h      = (float*)(ws);                    // 51,200,000 B
  float* m      = (float*)(ws + 51200000);         // 51,200,000 B
  float* e      = (float*)(ws + 102400000);        //    400,000 B (aliased below)
  float* q_star = (float*)(ws + 102800000);        //    131,072 B
  float* h_l    = (float*)(ws + 102931072);        //     65,536 B
  float* c_l    = (float*)(ws + 102996608);        //     65,536 B
  float* gmax   = (float*)(ws + 103062144);        //        512 B
  float* gsum   = (float*)(ws + 103062656);        //        512 B
  int*   startv = (int*)  (ws + 103063168);        //        528 B
  int*   rowstart = (int*)(ws + 103063808);        //    400,016 B
  int*   srcSorted= (int*)(ws + 103463824);        //  2,560,000 B
  int*   bsum   = (int*)  (ws + 106023824);        //        112 B
  int*   boff   = (int*)  (ws + 106023936);        //        112 B
  // 'e' buffer lifetimes: deg/cursor (CSR build) -> Whi/Wlo (MPNN loop,
  // 262,144 B <= 400,000) -> e scores (set2set)
  int*    deg    = (int*)e;
  int*    cursor = (int*)e;
  __bf16* Whi    = (__bf16*)(ws + 102400000);      //    131,072 B
  __bf16* Wlo    = (__bf16*)(ws + 102531072);      //    131,072 B

  const int* src = ei;
  const int* dst = ei + N_EDGES;

  // ---- CSR build (once; reused by all 3 MPNN steps) ----
  hipMemsetAsync(deg, 0, N_NODES * 4, stream);
  k_hist<<<(N_EDGES + 255) / 256, 256, 0, stream>>>(dst, deg);
  k_scan_part<<<SCAN_NB, 256, 0, stream>>>(deg, bsum);
  k_scan_mid<<<1, 32, 0, stream>>>(bsum, boff, rowstart);
  k_scan_final<<<SCAN_NB, 256, 0, stream>>>(deg, boff, rowstart);
  hipMemcpyAsync(cursor, rowstart, N_NODES * 4, hipMemcpyDeviceToDevice, stream);
  k_fill<<<(N_EDGES + 255) / 256, 256, 0, stream>>>(src, dst, cursor, srcSorted);

  // ---- one-time weight bf16 hi/lo split (overwrites deg/cursor region) ----
  k_wsplit<<<256, 256, 0, stream>>>(W_f, U_f, W_h, U_h, Whi, Wlo);

  k_input<<<N_NODES / 32, 256, 0, stream>>>(x, W_in, b_in, h);

  for (int step = 0; step < 3; ++step) {
    k_gather<<<(N_NODES + 3) / 4, 256, 0, stream>>>(h, rowstart, srcSorted, m);
    k_mgu<<<N_NODES / 32, 256, 0, stream>>>(h, m, Whi, Wlo, b_f, b_h);
  }

  k_bounds<<<1, 256, 0, stream>>>(batch, startv);
  hipMemsetAsync(q_star, 0, 262144, stream);

  for (int s = 0; s < 3; ++s) {
    k_lstm<<<NGRAPH, 256, 0, stream>>>(q_star, h_l, c_l, w_ih, w_hh, b_ih, b_hh);
    k_attn1<<<NGRAPH, 256, 0, stream>>>(h, q_star, startv, e, gmax, gsum);
    k_attn2<<<NGRAPH, 256, 0, stream>>>(h, e, startv, gmax, gsum, q_star);
  }

  k_pred<<<1, 128, 0, stream>>>(q_star, W_pred, b_pred, out);
}